// Round 11
// baseline (844.936 us; speedup 1.0000x reference)
//
#include <hip/hip_runtime.h>

#define INF 3.4e38f

// v_med3_u32: middle of three uints (sorted-insert primitive)
__device__ __forceinline__ unsigned med3u(unsigned a, unsigned b, unsigned c) {
    unsigned d;
    asm("v_med3_u32 %0, %1, %2, %3" : "=v"(d) : "v"(a), "v"(b), "v"(c));
    return d;
}

// insert u into sorted top-5 key list (k0<=k1<=k2<=k3<=k4): 5 VALU ops
__device__ __forceinline__ void ins5(unsigned u, unsigned& k0, unsigned& k1,
                                     unsigned& k2, unsigned& k3, unsigned& k4)
{
    unsigned n1 = med3u(k0, k1, u);
    unsigned n2 = med3u(k1, k2, u);
    unsigned n3 = med3u(k2, k3, u);
    unsigned n4 = med3u(k3, k4, u);
    k0 = k0 < u ? k0 : u;
    k1 = n1; k2 = n2; k3 = n3; k4 = n4;
}

// exact (value,index) insert with index tiebreak (resolution only)
__device__ __forceinline__ void ins3t(float e, int ei,
                                      float& c0, float& c1, float& c2,
                                      int& i0, int& i1, int& i2)
{
    bool l0 = (e < c0) || (e == c0 && ei < i0);
    bool l1 = (e < c1) || (e == c1 && ei < i1);
    bool l2 = (e < c2) || (e == c2 && ei < i2);
    c2 = l1 ? c1 : (l2 ? e  : c2);
    i2 = l1 ? i1 : (l2 ? ei : i2);
    c1 = l0 ? c0 : (l1 ? e  : c1);
    i1 = l0 ? i0 : (l1 ? ei : i1);
    c0 = l0 ? e  : c0;
    i0 = l0 ? ei : i0;
}

// ---------------- Pack centroids + zero gstats ----------------
__global__ __launch_bounds__(256) void fp_pack(
    const float* __restrict__ cents, float4* __restrict__ cpk,
    float* __restrict__ gstats, int M)
{
    if (blockIdx.x == 0) gstats[threadIdx.x] = 0.0f;   // 256 floats
    int m = blockIdx.x * 256 + threadIdx.x;
    if (m < M) {
        float x = cents[3*m], y = cents[3*m+1], z = cents[3*m+2];
        cpk[m] = make_float4(x, y, z, 0.5f * fmaf(x, x, fmaf(y, y, z*z)));
    }
}

// ---------------- Kernel A1: KNN select -> widx[3][N] ----------------
// Block = 512 thr / 8 waves / 64 vertices (lane = vertex). Wave w scans
// centroid range [Mw/8, M(w+1)/8) with wave-uniform cpk loads (SMEM path --
// measured best: 75us vs 119us forced-VMEM, R10). Packed key = (bits of
// 0.5*d^2+1e-4, low 11 bits = centroid index). Wave 0 merges the 8 per-wave
// top-5 lists and exact-resolves top-3 (guards quantization ties).
__global__ __launch_bounds__(512, 8) void fp_knn(
    const float* __restrict__ verts,
    const float* __restrict__ cents,
    const float4* __restrict__ cpk,
    int* __restrict__ widxG,
    int N, int M)
{
    __shared__ unsigned mk[8 * 5 * 64];   // 10KB merge buffer

    int t = threadIdx.x, lane = t & 63;
    int w = __builtin_amdgcn_readfirstlane(t >> 6);   // 0..7

    int v0 = blockIdx.x * 64;
    int vtx = v0 + lane;
    int vs  = vtx < N ? vtx : N - 1;
    float vx = verts[3*vs], vy = verts[3*vs+1], vz = verts[3*vs+2];

    // bias: s' = 0.5*|c|^2 - v.c + h = 0.5*d^2 + 1e-4  (>0, uint-order monotone)
    float h = 0.5f * fmaf(vx, vx, fmaf(vy, vy, vz*vz)) + 1e-4f;

    unsigned k0 = 0xFFFFFFFFu, k1 = 0xFFFFFFFFu, k2 = 0xFFFFFFFFu,
             k3 = 0xFFFFFFFFu, k4 = 0xFFFFFFFFu;

    int mw0 = (M * w) >> 3, mw1 = (M * (w + 1)) >> 3;
    #pragma unroll 8
    for (int m = mw0; m < mw1; ++m) {
        float4 c = cpk[m];                       // wave-uniform -> s_load
        float sp = fmaf(-vx, c.x, fmaf(-vy, c.y, fmaf(-vz, c.z, c.w + h)));
        unsigned u = (__float_as_uint(sp) & 0xFFFFF800u) | (unsigned)m;
        ins5(u, k0, k1, k2, k3, k4);
    }

    // publish per-wave top-5 (stride-1 across lanes: conflict-free)
    mk[(w*5 + 0)*64 + lane] = k0;
    mk[(w*5 + 1)*64 + lane] = k1;
    mk[(w*5 + 2)*64 + lane] = k2;
    mk[(w*5 + 3)*64 + lane] = k3;
    mk[(w*5 + 4)*64 + lane] = k4;
    __syncthreads();

    if (w == 0) {
        // fold in waves 1..7 (keys globally unique via index bits)
        #pragma unroll
        for (int ww = 1; ww < 8; ++ww) {
            unsigned e0 = mk[(ww*5 + 0)*64 + lane];
            unsigned e1 = mk[(ww*5 + 1)*64 + lane];
            unsigned e2 = mk[(ww*5 + 2)*64 + lane];
            unsigned e3 = mk[(ww*5 + 3)*64 + lane];
            unsigned e4 = mk[(ww*5 + 4)*64 + lane];
            ins5(e0, k0, k1, k2, k3, k4);
            ins5(e1, k0, k1, k2, k3, k4);
            ins5(e2, k0, k1, k2, k3, k4);
            ins5(e3, k0, k1, k2, k3, k4);
            ins5(e4, k0, k1, k2, k3, k4);
        }
        // exact d^2 for the 5 candidates from global cents (24KB, cache-hot),
        // exact top-3-of-5 with index tiebreak resolves quantization ties.
        int J0 = (int)(k0 & 2047u), J1 = (int)(k1 & 2047u), J2 = (int)(k2 & 2047u),
            J3 = (int)(k3 & 2047u), J4 = (int)(k4 & 2047u);
        float c0 = INF, c1 = INF, c2 = INF;
        int   i0 = 0x7fffffff, i1 = 0x7fffffff, i2 = 0x7fffffff;
        #pragma unroll
        for (int q = 0; q < 5; ++q) {
            int j = (q == 0) ? J0 : (q == 1) ? J1 : (q == 2) ? J2 : (q == 3) ? J3 : J4;
            float ax = cents[3*j], ay = cents[3*j+1], az = cents[3*j+2];
            float dx = vx - ax, dy = vy - ay, dz = vz - az;
            float dd = fmaf(dx, dx, fmaf(dy, dy, dz*dz));
            ins3t(dd, j, c0, c1, c2, i0, i1, i2);
        }
        if (vtx < N) {                     // coalesced across lanes
            widxG[vtx]         = i0;
            widxG[N + vtx]     = i1;
            widxG[2*N + vtx]   = i2;
        }
    }
}

// ---------------- Kernel A2: IDW interp + Linear1 -> hT + BN stats ----------------
// Block = 512 thr / 8 waves / 64 vertices. Recomputes exact d^2/weights from
// verts+cents (same fmaf sequence as fp_knn's resolve -> bit-identical),
// gathers feats (8 thr/vertex), interp to LDS, GEMM1 (wave w -> 16 cols).
// Epilogue: h values are already in acc[] registers -> shuffle-reduce the 64
// vertices per channel + one device-scope atomicAdd per wave per channel.
// This REPLACES the fp_reduce kernel (saves a 51MB hT re-read + a dispatch).
__global__ __launch_bounds__(512, 8) void fp_interp(
    const float* __restrict__ verts,
    const float* __restrict__ cents,
    const float* __restrict__ feats,
    const int* __restrict__ widxG,
    const float* __restrict__ W1,
    const float* __restrict__ b1,
    float* __restrict__ hT,
    float* __restrict__ gstats,
    int N)
{
    __shared__ __align__(16) float interpL[64 * 65];   // 16.64KB

    int t = threadIdx.x, lane = t & 63;
    int w  = __builtin_amdgcn_readfirstlane(t >> 6);
    int cw = w << 4;
    int v0 = blockIdx.x * 64;

    // gather: 8 threads/vertex, 8 feats each; weights recomputed per thread
    {
        int vloc = t >> 3, p = t & 7;
        int vtx = v0 + vloc;
        int vs  = vtx < N ? vtx : N - 1;
        int a0 = widxG[vs], a1 = widxG[N + vs], a2 = widxG[2*N + vs];
        float vx = verts[3*vs], vy = verts[3*vs+1], vz = verts[3*vs+2];

        float ax = cents[3*a0], ay = cents[3*a0+1], az = cents[3*a0+2];
        float bx = cents[3*a1], by = cents[3*a1+1], bz = cents[3*a1+2];
        float cx = cents[3*a2], cy = cents[3*a2+1], cz = cents[3*a2+2];
        float dx, dy, dz;
        dx = vx-ax; dy = vy-ay; dz = vz-az;
        float d0 = fmaf(dx, dx, fmaf(dy, dy, dz*dz));
        dx = vx-bx; dy = vy-by; dz = vz-bz;
        float d1 = fmaf(dx, dx, fmaf(dy, dy, dz*dz));
        dx = vx-cx; dy = vy-cy; dz = vz-cz;
        float d2 = fmaf(dx, dx, fmaf(dy, dy, dz*dz));
        bool z0 = (d0 == 0.0f), z1 = (d1 == 0.0f), z2 = (d2 == 0.0f);
        float w0, w1, w2;
        if (z0 || z1 || z2) {
            w0 = z0 ? 1.0f : 0.0f;
            w1 = z1 ? 1.0f : 0.0f;
            w2 = z2 ? 1.0f : 0.0f;
        } else {
            w0 = 1.0f / d0; w1 = 1.0f / d1; w2 = 1.0f / d2;
        }
        float winv = 1.0f / (w0 + w1 + w2);
        float u0 = w0 * winv, u1 = w1 * winv, u2 = w2 * winv;

        int fh = p * 8;
        const float4* f0 = (const float4*)(feats + (size_t)a0 * 64 + fh);
        const float4* f1 = (const float4*)(feats + (size_t)a1 * 64 + fh);
        const float4* f2 = (const float4*)(feats + (size_t)a2 * 64 + fh);
        float* dst = interpL + vloc * 65 + fh;
        #pragma unroll
        for (int q = 0; q < 2; ++q) {
            float4 A = f0[q], B = f1[q], C = f2[q];
            dst[4*q+0] = fmaf(u0, A.x, fmaf(u1, B.x, u2*C.x));
            dst[4*q+1] = fmaf(u0, A.y, fmaf(u1, B.y, u2*C.y));
            dst[4*q+2] = fmaf(u0, A.z, fmaf(u1, B.z, u2*C.z));
            dst[4*q+3] = fmaf(u0, A.w, fmaf(u1, B.w, u2*C.w));
        }
    }
    __syncthreads();

    // GEMM1: wave w -> cols [16w, 16w+16), lane -> vertex
    float acc[16];
    #pragma unroll
    for (int j = 0; j < 16; ++j) acc[j] = b1[cw + j];
    #pragma unroll 8
    for (int d = 0; d < 64; ++d) {
        float x = interpL[lane * 65 + d];
        const float* wr = W1 + d * 128 + cw;
        #pragma unroll
        for (int j = 0; j < 16; ++j) acc[j] = fmaf(x, wr[j], acc[j]);
    }
    int gv = v0 + lane;
    bool valid = gv < N;
    if (valid) {
        #pragma unroll
        for (int j = 0; j < 16; ++j)
            hT[(size_t)(cw + j) * N + gv] = acc[j];   // coalesced across lanes
    }

    // BN stats: reduce 64 vertices/channel in-register, 1 atomic/wave/channel
    #pragma unroll
    for (int j = 0; j < 16; ++j) {
        float v  = valid ? acc[j] : 0.0f;
        float vq = v * v;
        #pragma unroll
        for (int o = 32; o; o >>= 1) {
            v  += __shfl_xor(v, o);
            vq += __shfl_xor(vq, o);
        }
        if (lane == 0) {
            atomicAdd(&gstats[cw + j],       v);
            atomicAdd(&gstats[128 + cw + j], vq);
        }
    }
}

// ---------------- Kernel C: BN + ReLU + Linear2 (LDS-staged, read-once) ----------------
// 512 thr / 8 waves x 16 cols.
__global__ __launch_bounds__(512, 8) void fp_bn_mlp2(
    const float* __restrict__ hT,
    const float* __restrict__ gstats,
    const float* __restrict__ gamma,
    const float* __restrict__ beta,
    const float* __restrict__ W2,
    const float* __restrict__ b2,
    float* __restrict__ out,
    int N)
{
    __shared__ float scS[128], shS[128];
    __shared__ __align__(16) float hl[128 * 68];   // stage [128][68]; reuse [64][129]
    int t = threadIdx.x;
    if (t < 128) {
        float inv = 1.0f / (float)N;
        float mu  = gstats[t] * inv;
        float var = fmaf(-mu, mu, gstats[128 + t] * inv);
        var = fmaxf(var, 0.0f);
        float is = rsqrtf(var + 1e-5f);
        float sc = gamma[t] * is;
        scS[t] = sc;
        shS[t] = beta[t] - mu * sc;
    }
    __syncthreads();

    int r0 = blockIdx.x * 64;
    int N4 = N >> 2, r04 = r0 >> 2;
    const float4* hT4 = (const float4*)hT;

    // stage [128 ch][64 rows] with BN+ReLU applied: 2048 float4 / 512 thr
    #pragma unroll
    for (int jj = 0; jj < 4; ++jj) {
        int i4 = t + jj * 512;
        int k = i4 >> 4, r4 = i4 & 15;
        float4 v = make_float4(0.f, 0.f, 0.f, 0.f);
        if (r0 + 4*r4 < N) v = hT4[(size_t)k * N4 + r04 + r4];
        float sc = scS[k], sh = shS[k];
        float4 o;
        o.x = fmaxf(fmaf(v.x, sc, sh), 0.f);
        o.y = fmaxf(fmaf(v.y, sc, sh), 0.f);
        o.z = fmaxf(fmaf(v.z, sc, sh), 0.f);
        o.w = fmaxf(fmaf(v.w, sc, sh), 0.f);
        ((float4*)hl)[k * 17 + r4] = o;
    }
    __syncthreads();

    int lane = t & 63;
    int w  = __builtin_amdgcn_readfirstlane(t >> 6);
    int cw = w << 4;

    float acc[16];
    #pragma unroll
    for (int j = 0; j < 16; ++j) acc[j] = b2[cw + j];
    #pragma unroll 8
    for (int k = 0; k < 128; ++k) {
        float x = hl[k * 68 + lane];               // stride-1 across lanes
        const float* wr = W2 + k * 128 + cw;       // wave-uniform (SMEM) loads
        #pragma unroll
        for (int j = 0; j < 16; ++j) acc[j] = fmaf(x, wr[j], acc[j]);
    }
    __syncthreads();   // done reading staged hl

    // transpose via LDS (reuse hl as [64][129]) for coalesced float4 stores
    #pragma unroll
    for (int j = 0; j < 16; ++j) hl[lane * 129 + cw + j] = acc[j];
    __syncthreads();

    #pragma unroll
    for (int jj = 0; jj < 4; ++jj) {
        int i4 = t + jj * 512;
        int r = i4 >> 5, cq = (i4 & 31) << 2;
        int row = r0 + r;
        if (row < N) {
            float4 o4 = make_float4(hl[r*129 + cq],     hl[r*129 + cq + 1],
                                    hl[r*129 + cq + 2], hl[r*129 + cq + 3]);
            *(float4*)(out + (size_t)row * 128 + cq) = o4;
        }
    }
}

extern "C" void kernel_launch(void* const* d_in, const int* in_sizes, int n_in,
                              void* d_out, int out_size, void* d_ws, size_t ws_size,
                              hipStream_t stream)
{
    (void)n_in; (void)out_size; (void)ws_size;
    const float* verts = (const float*)d_in[0];
    const float* cents = (const float*)d_in[1];
    const float* feats = (const float*)d_in[2];
    const float* W1    = (const float*)d_in[3];
    const float* b1    = (const float*)d_in[4];
    const float* gamma = (const float*)d_in[5];
    const float* beta  = (const float*)d_in[6];
    const float* W2    = (const float*)d_in[7];
    const float* b2    = (const float*)d_in[8];
    float* out = (float*)d_out;

    int N = in_sizes[0] / 3;
    int M = in_sizes[1] / 3;

    float*  gstats = (float*)d_ws;                       // 256 floats
    float*  hT     = (float*)((char*)d_ws + 1024);       // [128, N]
    float4* cpk    = (float4*)(hT + (size_t)128 * N);    // [M] packed centroids
    int*    widxG  = (int*)(cpk + M);                    // [3, N] knn indices

    hipLaunchKernelGGL(fp_pack, dim3((M + 255) / 256), dim3(256), 0, stream,
                       cents, cpk, gstats, M);

    int nblk = (N + 63) / 64;
    hipLaunchKernelGGL(fp_knn, dim3(nblk), dim3(512), 0, stream,
                       verts, cents, cpk, widxG, N, M);

    hipLaunchKernelGGL(fp_interp, dim3(nblk), dim3(512), 0, stream,
                       verts, cents, feats, widxG, W1, b1, hT, gstats, N);

    hipLaunchKernelGGL(fp_bn_mlp2, dim3(nblk), dim3(512), 0, stream,
                       hT, gstats, gamma, beta, W2, b2, out, N);
}

// Round 12
// 250.791 us; speedup vs baseline: 3.3691x; 3.3691x over previous
//
#include <hip/hip_runtime.h>

#define INF 3.4e38f

// v_med3_u32: middle of three uints (sorted-insert primitive)
__device__ __forceinline__ unsigned med3u(unsigned a, unsigned b, unsigned c) {
    unsigned d;
    asm("v_med3_u32 %0, %1, %2, %3" : "=v"(d) : "v"(a), "v"(b), "v"(c));
    return d;
}

// insert u into sorted top-5 key list (k0<=k1<=k2<=k3<=k4): 5 VALU ops
__device__ __forceinline__ void ins5(unsigned u, unsigned& k0, unsigned& k1,
                                     unsigned& k2, unsigned& k3, unsigned& k4)
{
    unsigned n1 = med3u(k0, k1, u);
    unsigned n2 = med3u(k1, k2, u);
    unsigned n3 = med3u(k2, k3, u);
    unsigned n4 = med3u(k3, k4, u);
    k0 = k0 < u ? k0 : u;
    k1 = n1; k2 = n2; k3 = n3; k4 = n4;
}

// exact (value,index) insert with index tiebreak (resolution only)
__device__ __forceinline__ void ins3t(float e, int ei,
                                      float& c0, float& c1, float& c2,
                                      int& i0, int& i1, int& i2)
{
    bool l0 = (e < c0) || (e == c0 && ei < i0);
    bool l1 = (e < c1) || (e == c1 && ei < i1);
    bool l2 = (e < c2) || (e == c2 && ei < i2);
    c2 = l1 ? c1 : (l2 ? e  : c2);
    i2 = l1 ? i1 : (l2 ? ei : i2);
    c1 = l0 ? c0 : (l1 ? e  : c1);
    i1 = l0 ? i0 : (l1 ? ei : i1);
    c0 = l0 ? e  : c0;
    i0 = l0 ? ei : i0;
}

// ---------------- Pack centroids + zero gstats ----------------
__global__ __launch_bounds__(256) void fp_pack(
    const float* __restrict__ cents, float4* __restrict__ cpk,
    float* __restrict__ gstats, int M)
{
    if (blockIdx.x == 0) gstats[threadIdx.x] = 0.0f;   // 256 floats
    int m = blockIdx.x * 256 + threadIdx.x;
    if (m < M) {
        float x = cents[3*m], y = cents[3*m+1], z = cents[3*m+2];
        cpk[m] = make_float4(x, y, z, 0.5f * fmaf(x, x, fmaf(y, y, z*z)));
    }
}

// ---------------- Kernel A1: KNN select -> widx[3][N] ----------------
// Block = 512 thr / 8 waves / 64 vertices (lane = vertex). Wave w scans
// centroid range [Mw/8, M(w+1)/8) with wave-uniform cpk loads (SMEM path --
// measured best: 75us vs 119us forced-VMEM, R10). Packed key = (bits of
// 0.5*d^2+1e-4, low 11 bits = centroid index). Wave 0 merges the 8 per-wave
// top-5 lists and exact-resolves top-3 (guards quantization ties).
__global__ __launch_bounds__(512, 8) void fp_knn(
    const float* __restrict__ verts,
    const float* __restrict__ cents,
    const float4* __restrict__ cpk,
    int* __restrict__ widxG,
    int N, int M)
{
    __shared__ unsigned mk[8 * 5 * 64];   // 10KB merge buffer

    int t = threadIdx.x, lane = t & 63;
    int w = __builtin_amdgcn_readfirstlane(t >> 6);   // 0..7

    int v0 = blockIdx.x * 64;
    int vtx = v0 + lane;
    int vs  = vtx < N ? vtx : N - 1;
    float vx = verts[3*vs], vy = verts[3*vs+1], vz = verts[3*vs+2];

    // bias: s' = 0.5*|c|^2 - v.c + h = 0.5*d^2 + 1e-4  (>0, uint-order monotone)
    float h = 0.5f * fmaf(vx, vx, fmaf(vy, vy, vz*vz)) + 1e-4f;

    unsigned k0 = 0xFFFFFFFFu, k1 = 0xFFFFFFFFu, k2 = 0xFFFFFFFFu,
             k3 = 0xFFFFFFFFu, k4 = 0xFFFFFFFFu;

    int mw0 = (M * w) >> 3, mw1 = (M * (w + 1)) >> 3;
    #pragma unroll 8
    for (int m = mw0; m < mw1; ++m) {
        float4 c = cpk[m];                       // wave-uniform -> s_load
        float sp = fmaf(-vx, c.x, fmaf(-vy, c.y, fmaf(-vz, c.z, c.w + h)));
        unsigned u = (__float_as_uint(sp) & 0xFFFFF800u) | (unsigned)m;
        ins5(u, k0, k1, k2, k3, k4);
    }

    // publish per-wave top-5 (stride-1 across lanes: conflict-free)
    mk[(w*5 + 0)*64 + lane] = k0;
    mk[(w*5 + 1)*64 + lane] = k1;
    mk[(w*5 + 2)*64 + lane] = k2;
    mk[(w*5 + 3)*64 + lane] = k3;
    mk[(w*5 + 4)*64 + lane] = k4;
    __syncthreads();

    if (w == 0) {
        // fold in waves 1..7 (keys globally unique via index bits)
        #pragma unroll
        for (int ww = 1; ww < 8; ++ww) {
            unsigned e0 = mk[(ww*5 + 0)*64 + lane];
            unsigned e1 = mk[(ww*5 + 1)*64 + lane];
            unsigned e2 = mk[(ww*5 + 2)*64 + lane];
            unsigned e3 = mk[(ww*5 + 3)*64 + lane];
            unsigned e4 = mk[(ww*5 + 4)*64 + lane];
            ins5(e0, k0, k1, k2, k3, k4);
            ins5(e1, k0, k1, k2, k3, k4);
            ins5(e2, k0, k1, k2, k3, k4);
            ins5(e3, k0, k1, k2, k3, k4);
            ins5(e4, k0, k1, k2, k3, k4);
        }
        // exact d^2 for the 5 candidates from global cents (24KB, cache-hot),
        // exact top-3-of-5 with index tiebreak resolves quantization ties.
        int J0 = (int)(k0 & 2047u), J1 = (int)(k1 & 2047u), J2 = (int)(k2 & 2047u),
            J3 = (int)(k3 & 2047u), J4 = (int)(k4 & 2047u);
        float c0 = INF, c1 = INF, c2 = INF;
        int   i0 = 0x7fffffff, i1 = 0x7fffffff, i2 = 0x7fffffff;
        #pragma unroll
        for (int q = 0; q < 5; ++q) {
            int j = (q == 0) ? J0 : (q == 1) ? J1 : (q == 2) ? J2 : (q == 3) ? J3 : J4;
            float ax = cents[3*j], ay = cents[3*j+1], az = cents[3*j+2];
            float dx = vx - ax, dy = vy - ay, dz = vz - az;
            float dd = fmaf(dx, dx, fmaf(dy, dy, dz*dz));
            ins3t(dd, j, c0, c1, c2, i0, i1, i2);
        }
        if (vtx < N) {                     // coalesced across lanes
            widxG[vtx]         = i0;
            widxG[N + vtx]     = i1;
            widxG[2*N + vtx]   = i2;
        }
    }
}

// ---------------- Kernel A2: IDW interp + Linear1 -> hT ----------------
// Block = 512 thr / 8 waves / 64 vertices. Recomputes exact d^2/weights from
// verts+cents (same fmaf sequence as fp_knn's resolve -> bit-identical),
// gathers feats (8 thr/vertex), interp to LDS, GEMM1 (wave w -> 16 cols).
__global__ __launch_bounds__(512, 8) void fp_interp(
    const float* __restrict__ verts,
    const float* __restrict__ cents,
    const float* __restrict__ feats,
    const int* __restrict__ widxG,
    const float* __restrict__ W1,
    const float* __restrict__ b1,
    float* __restrict__ hT,
    int N)
{
    __shared__ __align__(16) float interpL[64 * 65];   // 16.64KB

    int t = threadIdx.x, lane = t & 63;
    int w  = __builtin_amdgcn_readfirstlane(t >> 6);
    int cw = w << 4;
    int v0 = blockIdx.x * 64;

    // gather: 8 threads/vertex, 8 feats each; weights recomputed per thread
    {
        int vloc = t >> 3, p = t & 7;
        int vtx = v0 + vloc;
        int vs  = vtx < N ? vtx : N - 1;
        int a0 = widxG[vs], a1 = widxG[N + vs], a2 = widxG[2*N + vs];
        float vx = verts[3*vs], vy = verts[3*vs+1], vz = verts[3*vs+2];

        float ax = cents[3*a0], ay = cents[3*a0+1], az = cents[3*a0+2];
        float bx = cents[3*a1], by = cents[3*a1+1], bz = cents[3*a1+2];
        float cx = cents[3*a2], cy = cents[3*a2+1], cz = cents[3*a2+2];
        float dx, dy, dz;
        dx = vx-ax; dy = vy-ay; dz = vz-az;
        float d0 = fmaf(dx, dx, fmaf(dy, dy, dz*dz));
        dx = vx-bx; dy = vy-by; dz = vz-bz;
        float d1 = fmaf(dx, dx, fmaf(dy, dy, dz*dz));
        dx = vx-cx; dy = vy-cy; dz = vz-cz;
        float d2 = fmaf(dx, dx, fmaf(dy, dy, dz*dz));
        bool z0 = (d0 == 0.0f), z1 = (d1 == 0.0f), z2 = (d2 == 0.0f);
        float w0, w1, w2;
        if (z0 || z1 || z2) {
            w0 = z0 ? 1.0f : 0.0f;
            w1 = z1 ? 1.0f : 0.0f;
            w2 = z2 ? 1.0f : 0.0f;
        } else {
            w0 = 1.0f / d0; w1 = 1.0f / d1; w2 = 1.0f / d2;
        }
        float winv = 1.0f / (w0 + w1 + w2);
        float u0 = w0 * winv, u1 = w1 * winv, u2 = w2 * winv;

        int fh = p * 8;
        const float4* f0 = (const float4*)(feats + (size_t)a0 * 64 + fh);
        const float4* f1 = (const float4*)(feats + (size_t)a1 * 64 + fh);
        const float4* f2 = (const float4*)(feats + (size_t)a2 * 64 + fh);
        float* dst = interpL + vloc * 65 + fh;
        #pragma unroll
        for (int q = 0; q < 2; ++q) {
            float4 A = f0[q], B = f1[q], C = f2[q];
            dst[4*q+0] = fmaf(u0, A.x, fmaf(u1, B.x, u2*C.x));
            dst[4*q+1] = fmaf(u0, A.y, fmaf(u1, B.y, u2*C.y));
            dst[4*q+2] = fmaf(u0, A.z, fmaf(u1, B.z, u2*C.z));
            dst[4*q+3] = fmaf(u0, A.w, fmaf(u1, B.w, u2*C.w));
        }
    }
    __syncthreads();

    // GEMM1: wave w -> cols [16w, 16w+16), lane -> vertex
    float acc[16];
    #pragma unroll
    for (int j = 0; j < 16; ++j) acc[j] = b1[cw + j];
    #pragma unroll 8
    for (int d = 0; d < 64; ++d) {
        float x = interpL[lane * 65 + d];
        const float* wr = W1 + d * 128 + cw;
        #pragma unroll
        for (int j = 0; j < 16; ++j) acc[j] = fmaf(x, wr[j], acc[j]);
    }
    int gv = v0 + lane;
    if (gv < N) {
        #pragma unroll
        for (int j = 0; j < 16; ++j)
            hT[(size_t)(cw + j) * N + gv] = acc[j];   // coalesced across lanes
    }
}

// ---------------- Reduce: BN stats straight from hT (L3-resident) ----------------
// 512 blocks: channel = bid & 127, segment = bid >> 7 (4 segs/channel).
__global__ __launch_bounds__(256) void fp_reduce(
    const float* __restrict__ hT,
    float* __restrict__ gstats, int N)
{
    __shared__ float red[8];
    int ch  = blockIdx.x & 127;
    int seg = blockIdx.x >> 7;
    const float* row = hT + (size_t)ch * N;
    float s = 0.0f, s2 = 0.0f;

    if ((N & 3) == 0) {
        int n4  = N >> 2;
        int len = (n4 + 3) >> 2;
        int a = seg * len, b = a + len; if (b > n4) b = n4;
        const float4* r4 = (const float4*)row;
        for (int i = a + threadIdx.x; i < b; i += 256) {
            float4 v = r4[i];
            s  += (v.x + v.y) + (v.z + v.w);
            s2 += fmaf(v.x, v.x, fmaf(v.y, v.y, fmaf(v.z, v.z, v.w * v.w)));
        }
    } else {
        int len = (N + 3) >> 2;
        int a = seg * len, b = a + len; if (b > N) b = N;
        for (int i = a + threadIdx.x; i < b; i += 256) {
            float v = row[i]; s += v; s2 = fmaf(v, v, s2);
        }
    }

    #pragma unroll
    for (int o = 32; o; o >>= 1) {
        s  += __shfl_xor(s, o);
        s2 += __shfl_xor(s2, o);
    }
    int w = threadIdx.x >> 6;
    if ((threadIdx.x & 63) == 0) { red[w] = s; red[4 + w] = s2; }
    __syncthreads();
    if (threadIdx.x == 0) {
        atomicAdd(&gstats[ch],       (red[0] + red[1]) + (red[2] + red[3]));
        atomicAdd(&gstats[128 + ch], (red[4] + red[5]) + (red[6] + red[7]));
    }
}

// ---------------- Kernel C: BN + ReLU + Linear2 (lane=col, W2 via VMEM) ----------------
// 512 thr / 8 waves. Wave w -> rows [8w, 8w+8); lane -> cols (lane, lane+64).
// x staged in LDS as [row][k] (BN+ReLU fused at stage). W2 rows read as
// per-lane coalesced global_load_dword (L2-hot, vmcnt-pipelined) instead of
// wave-uniform s_load (16KB sK$ can't hold 64KB W2 -> scalar-stall). Output
// stores coalesced by lane -> no transpose phase.
__global__ __launch_bounds__(512, 8) void fp_bn_mlp2(
    const float* __restrict__ hT,
    const float* __restrict__ gstats,
    const float* __restrict__ gamma,
    const float* __restrict__ beta,
    const float* __restrict__ W2,
    const float* __restrict__ b2,
    float* __restrict__ out,
    int N)
{
    __shared__ float scS[128], shS[128];
    __shared__ __align__(16) float xl[64 * 132];   // [row][k], 33.8KB
    int t = threadIdx.x;
    if (t < 128) {
        float inv = 1.0f / (float)N;
        float mu  = gstats[t] * inv;
        float var = fmaf(-mu, mu, gstats[128 + t] * inv);
        var = fmaxf(var, 0.0f);
        float is = rsqrtf(var + 1e-5f);
        float sc = gamma[t] * is;
        scS[t] = sc;
        shS[t] = beta[t] - mu * sc;
    }
    __syncthreads();

    int r0 = blockIdx.x * 64;
    int N4 = N >> 2, r04 = r0 >> 2;
    const float4* hT4 = (const float4*)hT;

    // stage x = relu(bn(h)) as [64 rows][128 k]: 2048 float4 loads / 512 thr
    #pragma unroll
    for (int jj = 0; jj < 4; ++jj) {
        int i4 = t + jj * 512;
        int k = i4 >> 4, r4 = i4 & 15;       // k: channel, r4: row-quad
        float4 v = make_float4(0.f, 0.f, 0.f, 0.f);
        if (r0 + 4*r4 < N) v = hT4[(size_t)k * N4 + r04 + r4];
        float sc = scS[k], sh = shS[k];
        xl[(4*r4 + 0) * 132 + k] = fmaxf(fmaf(v.x, sc, sh), 0.f);
        xl[(4*r4 + 1) * 132 + k] = fmaxf(fmaf(v.y, sc, sh), 0.f);
        xl[(4*r4 + 2) * 132 + k] = fmaxf(fmaf(v.z, sc, sh), 0.f);
        xl[(4*r4 + 3) * 132 + k] = fmaxf(fmaf(v.w, sc, sh), 0.f);
    }
    __syncthreads();

    int lane = t & 63;
    int w  = __builtin_amdgcn_readfirstlane(t >> 6);
    int rw = w << 3;                          // rows [rw, rw+8)

    float accL[8], accH[8];
    float blo = b2[lane], bhi = b2[lane + 64];
    #pragma unroll
    for (int i = 0; i < 8; ++i) { accL[i] = blo; accH[i] = bhi; }

    #pragma unroll 4
    for (int k2 = 0; k2 < 128; k2 += 2) {
        float2 xr[8];
        #pragma unroll
        for (int i = 0; i < 8; ++i)
            xr[i] = *(const float2*)&xl[(rw + i) * 132 + k2];   // ds_read_b64, wave-uniform
        float wl0 = W2[(size_t)k2 * 128 + lane];                // coalesced VMEM, L2-hot
        float wh0 = W2[(size_t)k2 * 128 + lane + 64];
        float wl1 = W2[(size_t)(k2 + 1) * 128 + lane];
        float wh1 = W2[(size_t)(k2 + 1) * 128 + lane + 64];
        #pragma unroll
        for (int i = 0; i < 8; ++i) {
            accL[i] = fmaf(xr[i].x, wl0, accL[i]);
            accH[i] = fmaf(xr[i].x, wh0, accH[i]);
        }
        #pragma unroll
        for (int i = 0; i < 8; ++i) {
            accL[i] = fmaf(xr[i].y, wl1, accL[i]);
            accH[i] = fmaf(xr[i].y, wh1, accH[i]);
        }
    }

    // stores: lane = col -> naturally coalesced, no transpose needed
    #pragma unroll
    for (int i = 0; i < 8; ++i) {
        int row = r0 + rw + i;
        if (row < N) {
            out[(size_t)row * 128 + lane]      = accL[i];
            out[(size_t)row * 128 + lane + 64] = accH[i];
        }
    }
}

extern "C" void kernel_launch(void* const* d_in, const int* in_sizes, int n_in,
                              void* d_out, int out_size, void* d_ws, size_t ws_size,
                              hipStream_t stream)
{
    (void)n_in; (void)out_size; (void)ws_size;
    const float* verts = (const float*)d_in[0];
    const float* cents = (const float*)d_in[1];
    const float* feats = (const float*)d_in[2];
    const float* W1    = (const float*)d_in[3];
    const float* b1    = (const float*)d_in[4];
    const float* gamma = (const float*)d_in[5];
    const float* beta  = (const float*)d_in[6];
    const float* W2    = (const float*)d_in[7];
    const float* b2    = (const float*)d_in[8];
    float* out = (float*)d_out;

    int N = in_sizes[0] / 3;
    int M = in_sizes[1] / 3;

    float*  gstats = (float*)d_ws;                       // 256 floats
    float*  hT     = (float*)((char*)d_ws + 1024);       // [128, N]
    float4* cpk    = (float4*)(hT + (size_t)128 * N);    // [M] packed centroids
    int*    widxG  = (int*)(cpk + M);                    // [3, N] knn indices

    hipLaunchKernelGGL(fp_pack, dim3((M + 255) / 256), dim3(256), 0, stream,
                       cents, cpk, gstats, M);

    int nblk = (N + 63) / 64;
    hipLaunchKernelGGL(fp_knn, dim3(nblk), dim3(512), 0, stream,
                       verts, cents, cpk, widxG, N, M);

    hipLaunchKernelGGL(fp_interp, dim3(nblk), dim3(512), 0, stream,
                       verts, cents, feats, widxG, W1, b1, hT, N);

    hipLaunchKernelGGL(fp_reduce, dim3(512), dim3(256), 0, stream,
                       hT, gstats, N);

    hipLaunchKernelGGL(fp_bn_mlp2, dim3(nblk), dim3(512), 0, stream,
                       hT, gstats, gamma, beta, W2, b2, out, N);
}

// Round 13
// 216.349 us; speedup vs baseline: 3.9054x; 1.1592x over previous
//
#include <hip/hip_runtime.h>

#define INF 3.4e38f

// v_med3_u32: middle of three uints (sorted-insert primitive)
__device__ __forceinline__ unsigned med3u(unsigned a, unsigned b, unsigned c) {
    unsigned d;
    asm("v_med3_u32 %0, %1, %2, %3" : "=v"(d) : "v"(a), "v"(b), "v"(c));
    return d;
}

// insert u into sorted top-5 key list (k0<=k1<=k2<=k3<=k4): 5 VALU ops
__device__ __forceinline__ void ins5(unsigned u, unsigned& k0, unsigned& k1,
                                     unsigned& k2, unsigned& k3, unsigned& k4)
{
    unsigned n1 = med3u(k0, k1, u);
    unsigned n2 = med3u(k1, k2, u);
    unsigned n3 = med3u(k2, k3, u);
    unsigned n4 = med3u(k3, k4, u);
    k0 = k0 < u ? k0 : u;
    k1 = n1; k2 = n2; k3 = n3; k4 = n4;
}

// exact (value,index) insert with index tiebreak (resolution only)
__device__ __forceinline__ void ins3t(float e, int ei,
                                      float& c0, float& c1, float& c2,
                                      int& i0, int& i1, int& i2)
{
    bool l0 = (e < c0) || (e == c0 && ei < i0);
    bool l1 = (e < c1) || (e == c1 && ei < i1);
    bool l2 = (e < c2) || (e == c2 && ei < i2);
    c2 = l1 ? c1 : (l2 ? e  : c2);
    i2 = l1 ? i1 : (l2 ? ei : i2);
    c1 = l0 ? c0 : (l1 ? e  : c1);
    i1 = l0 ? i0 : (l1 ? ei : i1);
    c0 = l0 ? e  : c0;
    i0 = l0 ? ei : i0;
}

// ---------------- Pack centroids + zero gstats ----------------
__global__ __launch_bounds__(256) void fp_pack(
    const float* __restrict__ cents, float4* __restrict__ cpk,
    float* __restrict__ gstats, int M)
{
    if (blockIdx.x == 0) gstats[threadIdx.x] = 0.0f;   // 256 floats
    int m = blockIdx.x * 256 + threadIdx.x;
    if (m < M) {
        float x = cents[3*m], y = cents[3*m+1], z = cents[3*m+2];
        cpk[m] = make_float4(x, y, z, 0.5f * fmaf(x, x, fmaf(y, y, z*z)));
    }
}

// ---------------- Kernel A1: KNN select -> widx[3][N] ----------------
// Block = 512 thr / 8 waves / 64 vertices (lane = vertex). Wave w scans
// [Mw/8, M(w+1)/8) with wave-uniform cpk loads (SMEM path, measured best).
// EXPLICIT 4-deep software pipeline: 8 float4 (32 SGPRs of cpk data) live at
// once so the s_load stream stays ahead of the ins5 chain (R8's SGPR=32
// build could only hold ~2 outstanding -> lgkmcnt drain every 2 iters).
// Packed key = (bits of 0.5*d^2+1e-4, low 11 bits = index). Wave 0 merges
// and exact-resolves top-3 (guards quantization ties).
__global__ __launch_bounds__(512, 8) void fp_knn(
    const float* __restrict__ verts,
    const float* __restrict__ cents,
    const float4* __restrict__ cpk,
    int* __restrict__ widxG,
    int N, int M)
{
    __shared__ unsigned mk[8 * 5 * 64];   // 10KB merge buffer

    int t = threadIdx.x, lane = t & 63;
    int w = __builtin_amdgcn_readfirstlane(t >> 6);   // 0..7

    int v0 = blockIdx.x * 64;
    int vtx = v0 + lane;
    int vs  = vtx < N ? vtx : N - 1;
    float vx = verts[3*vs], vy = verts[3*vs+1], vz = verts[3*vs+2];

    // bias: s' = 0.5*|c|^2 - v.c + h = 0.5*d^2 + 1e-4  (>0, uint-order monotone)
    float h = 0.5f * fmaf(vx, vx, fmaf(vy, vy, vz*vz)) + 1e-4f;

    unsigned k0 = 0xFFFFFFFFu, k1 = 0xFFFFFFFFu, k2 = 0xFFFFFFFFu,
             k3 = 0xFFFFFFFFu, k4 = 0xFFFFFFFFu;

#define PROC(c, midx)                                                          \
    {                                                                          \
        float sp = fmaf(-vx, (c).x, fmaf(-vy, (c).y,                           \
                        fmaf(-vz, (c).z, (c).w + h)));                         \
        unsigned u = (__float_as_uint(sp) & 0xFFFFF800u) | (unsigned)(midx);   \
        ins5(u, k0, k1, k2, k3, k4);                                           \
    }

    int mw0 = (M * w) >> 3, mw1 = (M * (w + 1)) >> 3;
    int m = mw0;
    int nPipe = (mw1 - mw0) & ~3;          // multiple of 4
    if (nPipe >= 8) {
        float4 p0 = cpk[m+0], p1 = cpk[m+1], p2 = cpk[m+2], p3 = cpk[m+3];
        for (; m + 8 <= mw0 + nPipe; m += 4) {
            float4 n0 = cpk[m+4], n1 = cpk[m+5], n2 = cpk[m+6], n3 = cpk[m+7];
            PROC(p0, m+0); PROC(p1, m+1); PROC(p2, m+2); PROC(p3, m+3);
            p0 = n0; p1 = n1; p2 = n2; p3 = n3;
        }
        PROC(p0, m+0); PROC(p1, m+1); PROC(p2, m+2); PROC(p3, m+3);
        m += 4;
    }
    for (; m < mw1; ++m) {                 // remainder (M not mult of 32)
        float4 c = cpk[m];
        PROC(c, m);
    }
#undef PROC

    // publish per-wave top-5 (stride-1 across lanes: conflict-free)
    mk[(w*5 + 0)*64 + lane] = k0;
    mk[(w*5 + 1)*64 + lane] = k1;
    mk[(w*5 + 2)*64 + lane] = k2;
    mk[(w*5 + 3)*64 + lane] = k3;
    mk[(w*5 + 4)*64 + lane] = k4;
    __syncthreads();

    if (w == 0) {
        // fold in waves 1..7 (keys globally unique via index bits)
        #pragma unroll
        for (int ww = 1; ww < 8; ++ww) {
            unsigned e0 = mk[(ww*5 + 0)*64 + lane];
            unsigned e1 = mk[(ww*5 + 1)*64 + lane];
            unsigned e2 = mk[(ww*5 + 2)*64 + lane];
            unsigned e3 = mk[(ww*5 + 3)*64 + lane];
            unsigned e4 = mk[(ww*5 + 4)*64 + lane];
            ins5(e0, k0, k1, k2, k3, k4);
            ins5(e1, k0, k1, k2, k3, k4);
            ins5(e2, k0, k1, k2, k3, k4);
            ins5(e3, k0, k1, k2, k3, k4);
            ins5(e4, k0, k1, k2, k3, k4);
        }
        // exact d^2 for the 5 candidates from global cents (24KB, cache-hot),
        // exact top-3-of-5 with index tiebreak resolves quantization ties.
        int J0 = (int)(k0 & 2047u), J1 = (int)(k1 & 2047u), J2 = (int)(k2 & 2047u),
            J3 = (int)(k3 & 2047u), J4 = (int)(k4 & 2047u);
        float c0 = INF, c1 = INF, c2 = INF;
        int   i0 = 0x7fffffff, i1 = 0x7fffffff, i2 = 0x7fffffff;
        #pragma unroll
        for (int q = 0; q < 5; ++q) {
            int j = (q == 0) ? J0 : (q == 1) ? J1 : (q == 2) ? J2 : (q == 3) ? J3 : J4;
            float ax = cents[3*j], ay = cents[3*j+1], az = cents[3*j+2];
            float dx = vx - ax, dy = vy - ay, dz = vz - az;
            float dd = fmaf(dx, dx, fmaf(dy, dy, dz*dz));
            ins3t(dd, j, c0, c1, c2, i0, i1, i2);
        }
        if (vtx < N) {                     // coalesced across lanes
            widxG[vtx]         = i0;
            widxG[N + vtx]     = i1;
            widxG[2*N + vtx]   = i2;
        }
    }
}

// ---------------- Kernel A2: IDW interp + Linear1 -> hT ----------------
// Block = 512 thr / 8 waves / 64 vertices. Recomputes exact d^2/weights from
// verts+cents (same fmaf sequence as fp_knn's resolve -> bit-identical),
// gathers feats (8 thr/vertex), interp to LDS, GEMM1 (wave w -> 16 cols).
__global__ __launch_bounds__(512, 8) void fp_interp(
    const float* __restrict__ verts,
    const float* __restrict__ cents,
    const float* __restrict__ feats,
    const int* __restrict__ widxG,
    const float* __restrict__ W1,
    const float* __restrict__ b1,
    float* __restrict__ hT,
    int N)
{
    __shared__ __align__(16) float interpL[64 * 65];   // 16.64KB

    int t = threadIdx.x, lane = t & 63;
    int w  = __builtin_amdgcn_readfirstlane(t >> 6);
    int cw = w << 4;
    int v0 = blockIdx.x * 64;

    // gather: 8 threads/vertex, 8 feats each; weights recomputed per thread
    {
        int vloc = t >> 3, p = t & 7;
        int vtx = v0 + vloc;
        int vs  = vtx < N ? vtx : N - 1;
        int a0 = widxG[vs], a1 = widxG[N + vs], a2 = widxG[2*N + vs];
        float vx = verts[3*vs], vy = verts[3*vs+1], vz = verts[3*vs+2];

        float ax = cents[3*a0], ay = cents[3*a0+1], az = cents[3*a0+2];
        float bx = cents[3*a1], by = cents[3*a1+1], bz = cents[3*a1+2];
        float cx = cents[3*a2], cy = cents[3*a2+1], cz = cents[3*a2+2];
        float dx, dy, dz;
        dx = vx-ax; dy = vy-ay; dz = vz-az;
        float d0 = fmaf(dx, dx, fmaf(dy, dy, dz*dz));
        dx = vx-bx; dy = vy-by; dz = vz-bz;
        float d1 = fmaf(dx, dx, fmaf(dy, dy, dz*dz));
        dx = vx-cx; dy = vy-cy; dz = vz-cz;
        float d2 = fmaf(dx, dx, fmaf(dy, dy, dz*dz));
        bool z0 = (d0 == 0.0f), z1 = (d1 == 0.0f), z2 = (d2 == 0.0f);
        float w0, w1, w2;
        if (z0 || z1 || z2) {
            w0 = z0 ? 1.0f : 0.0f;
            w1 = z1 ? 1.0f : 0.0f;
            w2 = z2 ? 1.0f : 0.0f;
        } else {
            w0 = 1.0f / d0; w1 = 1.0f / d1; w2 = 1.0f / d2;
        }
        float winv = 1.0f / (w0 + w1 + w2);
        float u0 = w0 * winv, u1 = w1 * winv, u2 = w2 * winv;

        int fh = p * 8;
        const float4* f0 = (const float4*)(feats + (size_t)a0 * 64 + fh);
        const float4* f1 = (const float4*)(feats + (size_t)a1 * 64 + fh);
        const float4* f2 = (const float4*)(feats + (size_t)a2 * 64 + fh);
        float* dst = interpL + vloc * 65 + fh;
        #pragma unroll
        for (int q = 0; q < 2; ++q) {
            float4 A = f0[q], B = f1[q], C = f2[q];
            dst[4*q+0] = fmaf(u0, A.x, fmaf(u1, B.x, u2*C.x));
            dst[4*q+1] = fmaf(u0, A.y, fmaf(u1, B.y, u2*C.y));
            dst[4*q+2] = fmaf(u0, A.z, fmaf(u1, B.z, u2*C.z));
            dst[4*q+3] = fmaf(u0, A.w, fmaf(u1, B.w, u2*C.w));
        }
    }
    __syncthreads();

    // GEMM1: wave w -> cols [16w, 16w+16), lane -> vertex
    float acc[16];
    #pragma unroll
    for (int j = 0; j < 16; ++j) acc[j] = b1[cw + j];
    #pragma unroll 8
    for (int d = 0; d < 64; ++d) {
        float x = interpL[lane * 65 + d];
        const float* wr = W1 + d * 128 + cw;
        #pragma unroll
        for (int j = 0; j < 16; ++j) acc[j] = fmaf(x, wr[j], acc[j]);
    }
    int gv = v0 + lane;
    if (gv < N) {
        #pragma unroll
        for (int j = 0; j < 16; ++j)
            hT[(size_t)(cw + j) * N + gv] = acc[j];   // coalesced across lanes
    }
}

// ---------------- Reduce: BN stats straight from hT (L3-resident) ----------------
// 512 blocks: channel = bid & 127, segment = bid >> 7 (4 segs/channel).
__global__ __launch_bounds__(256) void fp_reduce(
    const float* __restrict__ hT,
    float* __restrict__ gstats, int N)
{
    __shared__ float red[8];
    int ch  = blockIdx.x & 127;
    int seg = blockIdx.x >> 7;
    const float* row = hT + (size_t)ch * N;
    float s = 0.0f, s2 = 0.0f;

    if ((N & 3) == 0) {
        int n4  = N >> 2;
        int len = (n4 + 3) >> 2;
        int a = seg * len, b = a + len; if (b > n4) b = n4;
        const float4* r4 = (const float4*)row;
        for (int i = a + threadIdx.x; i < b; i += 256) {
            float4 v = r4[i];
            s  += (v.x + v.y) + (v.z + v.w);
            s2 += fmaf(v.x, v.x, fmaf(v.y, v.y, fmaf(v.z, v.z, v.w * v.w)));
        }
    } else {
        int len = (N + 3) >> 2;
        int a = seg * len, b = a + len; if (b > N) b = N;
        for (int i = a + threadIdx.x; i < b; i += 256) {
            float v = row[i]; s += v; s2 = fmaf(v, v, s2);
        }
    }

    #pragma unroll
    for (int o = 32; o; o >>= 1) {
        s  += __shfl_xor(s, o);
        s2 += __shfl_xor(s2, o);
    }
    int w = threadIdx.x >> 6;
    if ((threadIdx.x & 63) == 0) { red[w] = s; red[4 + w] = s2; }
    __syncthreads();
    if (threadIdx.x == 0) {
        atomicAdd(&gstats[ch],       (red[0] + red[1]) + (red[2] + red[3]));
        atomicAdd(&gstats[128 + ch], (red[4] + red[5]) + (red[6] + red[7]));
    }
}

// ---------------- Kernel C: BN + ReLU + Linear2 (LDS-staged, read-once) ----------------
// R8 version (proven). 512 thr / 8 waves x 16 cols.
__global__ __launch_bounds__(512, 8) void fp_bn_mlp2(
    const float* __restrict__ hT,
    const float* __restrict__ gstats,
    const float* __restrict__ gamma,
    const float* __restrict__ beta,
    const float* __restrict__ W2,
    const float* __restrict__ b2,
    float* __restrict__ out,
    int N)
{
    __shared__ float scS[128], shS[128];
    __shared__ __align__(16) float hl[128 * 68];   // stage [128][68]; reuse [64][129]
    int t = threadIdx.x;
    if (t < 128) {
        float inv = 1.0f / (float)N;
        float mu  = gstats[t] * inv;
        float var = fmaf(-mu, mu, gstats[128 + t] * inv);
        var = fmaxf(var, 0.0f);
        float is = rsqrtf(var + 1e-5f);
        float sc = gamma[t] * is;
        scS[t] = sc;
        shS[t] = beta[t] - mu * sc;
    }
    __syncthreads();

    int r0 = blockIdx.x * 64;
    int N4 = N >> 2, r04 = r0 >> 2;
    const float4* hT4 = (const float4*)hT;

    // stage [128 ch][64 rows] with BN+ReLU applied: 2048 float4 / 512 thr
    #pragma unroll
    for (int jj = 0; jj < 4; ++jj) {
        int i4 = t + jj * 512;
        int k = i4 >> 4, r4 = i4 & 15;
        float4 v = make_float4(0.f, 0.f, 0.f, 0.f);
        if (r0 + 4*r4 < N) v = hT4[(size_t)k * N4 + r04 + r4];
        float sc = scS[k], sh = shS[k];
        float4 o;
        o.x = fmaxf(fmaf(v.x, sc, sh), 0.f);
        o.y = fmaxf(fmaf(v.y, sc, sh), 0.f);
        o.z = fmaxf(fmaf(v.z, sc, sh), 0.f);
        o.w = fmaxf(fmaf(v.w, sc, sh), 0.f);
        ((float4*)hl)[k * 17 + r4] = o;
    }
    __syncthreads();

    int lane = t & 63;
    int w  = __builtin_amdgcn_readfirstlane(t >> 6);
    int cw = w << 4;

    float acc[16];
    #pragma unroll
    for (int j = 0; j < 16; ++j) acc[j] = b2[cw + j];
    #pragma unroll 8
    for (int k = 0; k < 128; ++k) {
        float x = hl[k * 68 + lane];               // stride-1 across lanes
        const float* wr = W2 + k * 128 + cw;       // wave-uniform (SMEM) loads
        #pragma unroll
        for (int j = 0; j < 16; ++j) acc[j] = fmaf(x, wr[j], acc[j]);
    }
    __syncthreads();   // done reading staged hl

    // transpose via LDS (reuse hl as [64][129]) for coalesced float4 stores
    #pragma unroll
    for (int j = 0; j < 16; ++j) hl[lane * 129 + cw + j] = acc[j];
    __syncthreads();

    #pragma unroll
    for (int jj = 0; jj < 4; ++jj) {
        int i4 = t + jj * 512;
        int r = i4 >> 5, cq = (i4 & 31) << 2;
        int row = r0 + r;
        if (row < N) {
            float4 o4 = make_float4(hl[r*129 + cq],     hl[r*129 + cq + 1],
                                    hl[r*129 + cq + 2], hl[r*129 + cq + 3]);
            *(float4*)(out + (size_t)row * 128 + cq) = o4;
        }
    }
}

extern "C" void kernel_launch(void* const* d_in, const int* in_sizes, int n_in,
                              void* d_out, int out_size, void* d_ws, size_t ws_size,
                              hipStream_t stream)
{
    (void)n_in; (void)out_size; (void)ws_size;
    const float* verts = (const float*)d_in[0];
    const float* cents = (const float*)d_in[1];
    const float* feats = (const float*)d_in[2];
    const float* W1    = (const float*)d_in[3];
    const float* b1    = (const float*)d_in[4];
    const float* gamma = (const float*)d_in[5];
    const float* beta  = (const float*)d_in[6];
    const float* W2    = (const float*)d_in[7];
    const float* b2    = (const float*)d_in[8];
    float* out = (float*)d_out;

    int N = in_sizes[0] / 3;
    int M = in_sizes[1] / 3;

    float*  gstats = (float*)d_ws;                       // 256 floats
    float*  hT     = (float*)((char*)d_ws + 1024);       // [128, N]
    float4* cpk    = (float4*)(hT + (size_t)128 * N);    // [M] packed centroids
    int*    widxG  = (int*)(cpk + M);                    // [3, N] knn indices

    hipLaunchKernelGGL(fp_pack, dim3((M + 255) / 256), dim3(256), 0, stream,
                       cents, cpk, gstats, M);

    int nblk = (N + 63) / 64;
    hipLaunchKernelGGL(fp_knn, dim3(nblk), dim3(512), 0, stream,
                       verts, cents, cpk, widxG, N, M);

    hipLaunchKernelGGL(fp_interp, dim3(nblk), dim3(512), 0, stream,
                       verts, cents, feats, widxG, W1, b1, hT, N);

    hipLaunchKernelGGL(fp_reduce, dim3(512), dim3(256), 0, stream,
                       hT, gstats, N);

    hipLaunchKernelGGL(fp_bn_mlp2, dim3(nblk), dim3(512), 0, stream,
                       hT, gstats, gamma, beta, W2, b2, out, N);
}

// Round 14
// 210.192 us; speedup vs baseline: 4.0198x; 1.0293x over previous
//
#include <hip/hip_runtime.h>

#define INF 3.4e38f

// v_med3_u32: middle of three uints (sorted-insert primitive)
__device__ __forceinline__ unsigned med3u(unsigned a, unsigned b, unsigned c) {
    unsigned d;
    asm("v_med3_u32 %0, %1, %2, %3" : "=v"(d) : "v"(a), "v"(b), "v"(c));
    return d;
}

// insert u into sorted top-5 key list (k0<=k1<=k2<=k3<=k4): 5 VALU ops
__device__ __forceinline__ void ins5(unsigned u, unsigned& k0, unsigned& k1,
                                     unsigned& k2, unsigned& k3, unsigned& k4)
{
    unsigned n1 = med3u(k0, k1, u);
    unsigned n2 = med3u(k1, k2, u);
    unsigned n3 = med3u(k2, k3, u);
    unsigned n4 = med3u(k3, k4, u);
    k0 = k0 < u ? k0 : u;
    k1 = n1; k2 = n2; k3 = n3; k4 = n4;
}

// exact (value,index) insert with index tiebreak (resolution only)
__device__ __forceinline__ void ins3t(float e, int ei,
                                      float& c0, float& c1, float& c2,
                                      int& i0, int& i1, int& i2)
{
    bool l0 = (e < c0) || (e == c0 && ei < i0);
    bool l1 = (e < c1) || (e == c1 && ei < i1);
    bool l2 = (e < c2) || (e == c2 && ei < i2);
    c2 = l1 ? c1 : (l2 ? e  : c2);
    i2 = l1 ? i1 : (l2 ? ei : i2);
    c1 = l0 ? c0 : (l1 ? e  : c1);
    i1 = l0 ? i0 : (l1 ? ei : i1);
    c0 = l0 ? e  : c0;
    i0 = l0 ? ei : i0;
}

// ---------------- Pack centroids + zero gstats ----------------
__global__ __launch_bounds__(256) void fp_pack(
    const float* __restrict__ cents, float4* __restrict__ cpk,
    float* __restrict__ gstats, int M)
{
    if (blockIdx.x == 0) gstats[threadIdx.x] = 0.0f;   // 256 floats
    int m = blockIdx.x * 256 + threadIdx.x;
    if (m < M) {
        float x = cents[3*m], y = cents[3*m+1], z = cents[3*m+2];
        cpk[m] = make_float4(x, y, z, 0.5f * fmaf(x, x, fmaf(y, y, z*z)));
    }
}

// ---------------- Kernel A: KNN + IDW interp + Linear1 -> hT ----------------
// Merged fp_knn + fp_interp (saves a dispatch gap + widx global round-trip).
// Block = 512 thr / 8 waves / 64 vertices (lane = vertex). Wave w scans
// [Mw/8, M(w+1)/8) with wave-uniform cpk loads (SMEM path), 4-deep software
// pipeline (8 float4 = 32 SGPRs of cpk data in flight -- R13: 75->60.5us).
// Packed key = (bits of 0.5*d^2+1e-4, low 11 bits = index). Wave 0 merges,
// exact-resolves top-3 (guards quantization ties) and publishes widx/wwt to
// LDS; gather (8 thr/vertex) + GEMM1 (wave w -> 16 cols) follow in-kernel.
__global__ __launch_bounds__(512, 8) void fp_main(
    const float* __restrict__ verts,
    const float* __restrict__ cents,
    const float4* __restrict__ cpk,
    const float* __restrict__ feats,
    const float* __restrict__ W1,
    const float* __restrict__ b1,
    float* __restrict__ hT,
    int N, int M)
{
    // aliased region: merge buf uint[8][5][64] (10KB) / interpL [64][65] (16.64KB)
    __shared__ __align__(16) float smem[4160];
    __shared__ int   widx[64][3];
    __shared__ float wwt [64][3];
    float*    interpL = smem;
    unsigned* mk      = (unsigned*)smem;

    int t = threadIdx.x, lane = t & 63;
    int w  = __builtin_amdgcn_readfirstlane(t >> 6);   // 0..7
    int cw = w << 4;                                    // 16-col GEMM slice

    int v0 = blockIdx.x * 64;
    int vtx = v0 + lane;
    int vs  = vtx < N ? vtx : N - 1;
    float vx = verts[3*vs], vy = verts[3*vs+1], vz = verts[3*vs+2];

    // bias: s' = 0.5*|c|^2 - v.c + h = 0.5*d^2 + 1e-4  (>0, uint-order monotone)
    float h = 0.5f * fmaf(vx, vx, fmaf(vy, vy, vz*vz)) + 1e-4f;

    unsigned k0 = 0xFFFFFFFFu, k1 = 0xFFFFFFFFu, k2 = 0xFFFFFFFFu,
             k3 = 0xFFFFFFFFu, k4 = 0xFFFFFFFFu;

#define PROC(c, midx)                                                          \
    {                                                                          \
        float sp = fmaf(-vx, (c).x, fmaf(-vy, (c).y,                           \
                        fmaf(-vz, (c).z, (c).w + h)));                         \
        unsigned u = (__float_as_uint(sp) & 0xFFFFF800u) | (unsigned)(midx);   \
        ins5(u, k0, k1, k2, k3, k4);                                           \
    }

    int mw0 = (M * w) >> 3, mw1 = (M * (w + 1)) >> 3;
    int m = mw0;
    int nPipe = (mw1 - mw0) & ~3;          // multiple of 4
    if (nPipe >= 8) {
        float4 p0 = cpk[m+0], p1 = cpk[m+1], p2 = cpk[m+2], p3 = cpk[m+3];
        for (; m + 8 <= mw0 + nPipe; m += 4) {
            float4 n0 = cpk[m+4], n1 = cpk[m+5], n2 = cpk[m+6], n3 = cpk[m+7];
            PROC(p0, m+0); PROC(p1, m+1); PROC(p2, m+2); PROC(p3, m+3);
            p0 = n0; p1 = n1; p2 = n2; p3 = n3;
        }
        PROC(p0, m+0); PROC(p1, m+1); PROC(p2, m+2); PROC(p3, m+3);
        m += 4;
    }
    for (; m < mw1; ++m) {                 // remainder (M not mult of 32)
        float4 c = cpk[m];
        PROC(c, m);
    }
#undef PROC

    // publish per-wave top-5 (stride-1 across lanes: conflict-free)
    mk[(w*5 + 0)*64 + lane] = k0;
    mk[(w*5 + 1)*64 + lane] = k1;
    mk[(w*5 + 2)*64 + lane] = k2;
    mk[(w*5 + 3)*64 + lane] = k3;
    mk[(w*5 + 4)*64 + lane] = k4;
    __syncthreads();

    if (w == 0) {
        // fold in waves 1..7 (keys globally unique via index bits)
        #pragma unroll
        for (int ww = 1; ww < 8; ++ww) {
            unsigned e0 = mk[(ww*5 + 0)*64 + lane];
            unsigned e1 = mk[(ww*5 + 1)*64 + lane];
            unsigned e2 = mk[(ww*5 + 2)*64 + lane];
            unsigned e3 = mk[(ww*5 + 3)*64 + lane];
            unsigned e4 = mk[(ww*5 + 4)*64 + lane];
            ins5(e0, k0, k1, k2, k3, k4);
            ins5(e1, k0, k1, k2, k3, k4);
            ins5(e2, k0, k1, k2, k3, k4);
            ins5(e3, k0, k1, k2, k3, k4);
            ins5(e4, k0, k1, k2, k3, k4);
        }
        // exact d^2 for the 5 candidates from global cents (24KB, cache-hot),
        // exact top-3-of-5 with index tiebreak resolves quantization ties.
        int J0 = (int)(k0 & 2047u), J1 = (int)(k1 & 2047u), J2 = (int)(k2 & 2047u),
            J3 = (int)(k3 & 2047u), J4 = (int)(k4 & 2047u);
        float c0 = INF, c1 = INF, c2 = INF;
        int   i0 = 0x7fffffff, i1 = 0x7fffffff, i2 = 0x7fffffff;
        #pragma unroll
        for (int q = 0; q < 5; ++q) {
            int j = (q == 0) ? J0 : (q == 1) ? J1 : (q == 2) ? J2 : (q == 3) ? J3 : J4;
            float ax = cents[3*j], ay = cents[3*j+1], az = cents[3*j+2];
            float dx = vx - ax, dy = vy - ay, dz = vz - az;
            float dd = fmaf(dx, dx, fmaf(dy, dy, dz*dz));
            ins3t(dd, j, c0, c1, c2, i0, i1, i2);
        }
        float d0 = c0, d1 = c1, d2 = c2;
        bool z0 = (d0 == 0.0f), z1 = (d1 == 0.0f), z2 = (d2 == 0.0f);
        float w0, w1, w2;
        if (z0 || z1 || z2) {
            w0 = z0 ? 1.0f : 0.0f;
            w1 = z1 ? 1.0f : 0.0f;
            w2 = z2 ? 1.0f : 0.0f;
        } else {
            w0 = 1.0f / d0; w1 = 1.0f / d1; w2 = 1.0f / d2;
        }
        float winv = 1.0f / (w0 + w1 + w2);
        widx[lane][0] = i0; wwt[lane][0] = w0 * winv;
        widx[lane][1] = i1; wwt[lane][1] = w1 * winv;
        widx[lane][2] = i2; wwt[lane][2] = w2 * winv;
    }
    __syncthreads();   // mk reads done; widx/wwt published

    // gather: 8 threads/vertex, 8 feats each (overwrites merge-buf region)
    {
        int vloc = t >> 3, p = t & 7;
        int a0 = widx[vloc][0], a1 = widx[vloc][1], a2 = widx[vloc][2];
        float u0 = wwt[vloc][0], u1 = wwt[vloc][1], u2 = wwt[vloc][2];
        int fh = p * 8;
        const float4* f0 = (const float4*)(feats + (size_t)a0 * 64 + fh);
        const float4* f1 = (const float4*)(feats + (size_t)a1 * 64 + fh);
        const float4* f2 = (const float4*)(feats + (size_t)a2 * 64 + fh);
        float* dst = interpL + vloc * 65 + fh;
        #pragma unroll
        for (int q = 0; q < 2; ++q) {
            float4 A = f0[q], B = f1[q], C = f2[q];
            dst[4*q+0] = fmaf(u0, A.x, fmaf(u1, B.x, u2*C.x));
            dst[4*q+1] = fmaf(u0, A.y, fmaf(u1, B.y, u2*C.y));
            dst[4*q+2] = fmaf(u0, A.z, fmaf(u1, B.z, u2*C.z));
            dst[4*q+3] = fmaf(u0, A.w, fmaf(u1, B.w, u2*C.w));
        }
    }
    __syncthreads();

    // GEMM1: wave w -> cols [16w, 16w+16), lane -> vertex
    float acc[16];
    #pragma unroll
    for (int j = 0; j < 16; ++j) acc[j] = b1[cw + j];
    #pragma unroll 8
    for (int d = 0; d < 64; ++d) {
        float x = interpL[lane * 65 + d];
        const float* wr = W1 + d * 128 + cw;
        #pragma unroll
        for (int j = 0; j < 16; ++j) acc[j] = fmaf(x, wr[j], acc[j]);
    }
    int gv = v0 + lane;
    if (gv < N) {
        #pragma unroll
        for (int j = 0; j < 16; ++j)
            hT[(size_t)(cw + j) * N + gv] = acc[j];   // coalesced across lanes
    }
}

// ---------------- Reduce: BN stats straight from hT (L3-resident) ----------------
// 512 blocks: channel = bid & 127, segment = bid >> 7 (4 segs/channel).
__global__ __launch_bounds__(256) void fp_reduce(
    const float* __restrict__ hT,
    float* __restrict__ gstats, int N)
{
    __shared__ float red[8];
    int ch  = blockIdx.x & 127;
    int seg = blockIdx.x >> 7;
    const float* row = hT + (size_t)ch * N;
    float s = 0.0f, s2 = 0.0f;

    if ((N & 3) == 0) {
        int n4  = N >> 2;
        int len = (n4 + 3) >> 2;
        int a = seg * len, b = a + len; if (b > n4) b = n4;
        const float4* r4 = (const float4*)row;
        for (int i = a + threadIdx.x; i < b; i += 256) {
            float4 v = r4[i];
            s  += (v.x + v.y) + (v.z + v.w);
            s2 += fmaf(v.x, v.x, fmaf(v.y, v.y, fmaf(v.z, v.z, v.w * v.w)));
        }
    } else {
        int len = (N + 3) >> 2;
        int a = seg * len, b = a + len; if (b > N) b = N;
        for (int i = a + threadIdx.x; i < b; i += 256) {
            float v = row[i]; s += v; s2 = fmaf(v, v, s2);
        }
    }

    #pragma unroll
    for (int o = 32; o; o >>= 1) {
        s  += __shfl_xor(s, o);
        s2 += __shfl_xor(s2, o);
    }
    int w = threadIdx.x >> 6;
    if ((threadIdx.x & 63) == 0) { red[w] = s; red[4 + w] = s2; }
    __syncthreads();
    if (threadIdx.x == 0) {
        atomicAdd(&gstats[ch],       (red[0] + red[1]) + (red[2] + red[3]));
        atomicAdd(&gstats[128 + ch], (red[4] + red[5]) + (red[6] + red[7]));
    }
}

// ---------------- Kernel C: BN + ReLU + Linear2 (LDS-staged, read-once) ----------------
// R8 version (proven). 512 thr / 8 waves x 16 cols.
__global__ __launch_bounds__(512, 8) void fp_bn_mlp2(
    const float* __restrict__ hT,
    const float* __restrict__ gstats,
    const float* __restrict__ gamma,
    const float* __restrict__ beta,
    const float* __restrict__ W2,
    const float* __restrict__ b2,
    float* __restrict__ out,
    int N)
{
    __shared__ float scS[128], shS[128];
    __shared__ __align__(16) float hl[128 * 68];   // stage [128][68]; reuse [64][129]
    int t = threadIdx.x;
    if (t < 128) {
        float inv = 1.0f / (float)N;
        float mu  = gstats[t] * inv;
        float var = fmaf(-mu, mu, gstats[128 + t] * inv);
        var = fmaxf(var, 0.0f);
        float is = rsqrtf(var + 1e-5f);
        float sc = gamma[t] * is;
        scS[t] = sc;
        shS[t] = beta[t] - mu * sc;
    }
    __syncthreads();

    int r0 = blockIdx.x * 64;
    int N4 = N >> 2, r04 = r0 >> 2;
    const float4* hT4 = (const float4*)hT;

    // stage [128 ch][64 rows] with BN+ReLU applied: 2048 float4 / 512 thr
    #pragma unroll
    for (int jj = 0; jj < 4; ++jj) {
        int i4 = t + jj * 512;
        int k = i4 >> 4, r4 = i4 & 15;
        float4 v = make_float4(0.f, 0.f, 0.f, 0.f);
        if (r0 + 4*r4 < N) v = hT4[(size_t)k * N4 + r04 + r4];
        float sc = scS[k], sh = shS[k];
        float4 o;
        o.x = fmaxf(fmaf(v.x, sc, sh), 0.f);
        o.y = fmaxf(fmaf(v.y, sc, sh), 0.f);
        o.z = fmaxf(fmaf(v.z, sc, sh), 0.f);
        o.w = fmaxf(fmaf(v.w, sc, sh), 0.f);
        ((float4*)hl)[k * 17 + r4] = o;
    }
    __syncthreads();

    int lane = t & 63;
    int w  = __builtin_amdgcn_readfirstlane(t >> 6);
    int cw = w << 4;

    float acc[16];
    #pragma unroll
    for (int j = 0; j < 16; ++j) acc[j] = b2[cw + j];
    #pragma unroll 8
    for (int k = 0; k < 128; ++k) {
        float x = hl[k * 68 + lane];               // stride-1 across lanes
        const float* wr = W2 + k * 128 + cw;       // wave-uniform (SMEM) loads
        #pragma unroll
        for (int j = 0; j < 16; ++j) acc[j] = fmaf(x, wr[j], acc[j]);
    }
    __syncthreads();   // done reading staged hl

    // transpose via LDS (reuse hl as [64][129]) for coalesced float4 stores
    #pragma unroll
    for (int j = 0; j < 16; ++j) hl[lane * 129 + cw + j] = acc[j];
    __syncthreads();

    #pragma unroll
    for (int jj = 0; jj < 4; ++jj) {
        int i4 = t + jj * 512;
        int r = i4 >> 5, cq = (i4 & 31) << 2;
        int row = r0 + r;
        if (row < N) {
            float4 o4 = make_float4(hl[r*129 + cq],     hl[r*129 + cq + 1],
                                    hl[r*129 + cq + 2], hl[r*129 + cq + 3]);
            *(float4*)(out + (size_t)row * 128 + cq) = o4;
        }
    }
}

extern "C" void kernel_launch(void* const* d_in, const int* in_sizes, int n_in,
                              void* d_out, int out_size, void* d_ws, size_t ws_size,
                              hipStream_t stream)
{
    (void)n_in; (void)out_size; (void)ws_size;
    const float* verts = (const float*)d_in[0];
    const float* cents = (const float*)d_in[1];
    const float* feats = (const float*)d_in[2];
    const float* W1    = (const float*)d_in[3];
    const float* b1    = (const float*)d_in[4];
    const float* gamma = (const float*)d_in[5];
    const float* beta  = (const float*)d_in[6];
    const float* W2    = (const float*)d_in[7];
    const float* b2    = (const float*)d_in[8];
    float* out = (float*)d_out;

    int N = in_sizes[0] / 3;
    int M = in_sizes[1] / 3;

    float*  gstats = (float*)d_ws;                       // 256 floats
    float*  hT     = (float*)((char*)d_ws + 1024);       // [128, N]
    float4* cpk    = (float4*)(hT + (size_t)128 * N);    // [M] packed centroids

    hipLaunchKernelGGL(fp_pack, dim3((M + 255) / 256), dim3(256), 0, stream,
                       cents, cpk, gstats, M);

    int nblk = (N + 63) / 64;
    hipLaunchKernelGGL(fp_main, dim3(nblk), dim3(512), 0, stream,
                       verts, cents, cpk, feats, W1, b1, hT, N, M);

    hipLaunchKernelGGL(fp_reduce, dim3(512), dim3(256), 0, stream,
                       hT, gstats, N);

    hipLaunchKernelGGL(fp_bn_mlp2, dim3(nblk), dim3(512), 0, stream,
                       hT, gstats, gamma, beta, W2, b2, out, N);
}